// Round 1
// baseline (1454.970 us; speedup 1.0000x reference)
//
#include <hip/hip_runtime.h>

#define P_PIX 22500
#define HB 61
#define HBP 64
#define CHUNK 64
#define HSPLIT 8

// ---------------------------------------------------------------------------
// RGB-uv soft histogram.  grid (48 = B*3, HSPLIT), block 256.
// Each block: one (b, c) pair, 1/HSPLIT of the pixels.
// Wave w owns u-bins [16w, 16w+16); thread tile = 4x4 bins; atomicAdd epilogue.
// Optional 3x3 color transform msc (illuminant branch maps pixels first).
// ---------------------------------------------------------------------------
__global__ __launch_bounds__(256) void hist_kernel(
    const float* __restrict__ img, const float* __restrict__ su,
    const float* __restrict__ sv, const float* __restrict__ cw,
    const float* __restrict__ msc, float* __restrict__ hist)
{
    const int bc = blockIdx.x;
    const int b = bc / 3, c = bc % 3;
    const int split = blockIdx.y;
    const int tid = threadIdx.x;

    __shared__ __align__(16) float sku[CHUNK][HBP];   // w * exp(-(u-bin)^2/su^2)
    __shared__ __align__(16) float skv[CHUNK][HBP];   // exp(-(v-bin)^2/sv^2)
    __shared__ float suu[CHUNK], svv[CHUNK], sww[CHUNK];

    const float sig_u = su[c], sig_v = sv[c];
    const float inv_su2 = 1.f / (sig_u * sig_u);
    const float inv_sv2 = 1.f / (sig_v * sig_v);
    const float cwc = cw[c];
    const float Ru = 4.6f * sig_u;   // exp(-21.2) ~ 6e-10 tail cutoff

    const bool hasM = (msc != nullptr);
    float m00=0,m01=0,m02=0,m10=0,m11=0,m12=0,m20=0,m21=0,m22=0;
    if (hasM) {
        const float* mp = msc + b * 9;
        m00=mp[0]; m01=mp[1]; m02=mp[2];
        m10=mp[3]; m11=mp[4]; m12=mp[5];
        m20=mp[6]; m21=mp[7]; m22=mp[8];
    }

    const int w    = tid >> 6;         // wave id 0..3 -> u-bin group [16w,16w+16)
    const int usub = tid & 3;          // 4 u-bins within the wave's group
    const int tv   = (tid >> 2) & 15;  // v tile
    const int ub0  = w * 16 + usub * 4;
    const int vb0  = tv * 4;
    const float wave_lo = -3.f + 0.1f * (float)(w * 16);
    const float wave_hi = wave_lo + 1.5f;

    float acc[4][4];
#pragma unroll
    for (int i = 0; i < 4; ++i)
#pragma unroll
        for (int j = 0; j < 4; ++j) acc[i][j] = 0.f;

    for (int base = split * CHUNK; base < P_PIX; base += HSPLIT * CHUNK) {
        // phase 1: u, v, weight for 64 pixels
        if (tid < CHUNK) {
            int pp = base + tid;
            float u = 0.f, v = 0.f, wgt = 0.f;
            if (pp < P_PIX) {
                const float* ip = img + (size_t)b * 3 * P_PIX + pp;
                float r = ip[0], g = ip[P_PIX], bl = ip[2 * P_PIX];
                if (hasM) {
                    float r2 = m00 * r + m01 * g + m02 * bl;
                    float g2 = m10 * r + m11 * g + m12 * bl;
                    float b2 = m20 * r + m21 * g + m22 * bl;
                    r = r2; g = g2; bl = b2;
                }
                r  = fminf(fmaxf(r, 0.f), 1.f);
                g  = fminf(fmaxf(g, 0.f), 1.f);
                bl = fminf(fmaxf(bl, 0.f), 1.f);
                float Iy = sqrtf(r * r + g * g + bl * bl);
                float lr = __logf(r + 1e-6f);
                float lg = __logf(g + 1e-6f);
                float lb = __logf(bl + 1e-6f);
                if (c == 0)      { u = lr - lg; v = lr - lb; }
                else if (c == 1) { u = lg - lr; v = lg - lb; }
                else             { u = lb - lr; v = lb - lg; }
                wgt = Iy * cwc;
            }
            suu[tid] = u; svv[tid] = v; sww[tid] = wgt;
        }
        __syncthreads();
        // phase 2: Gaussian kernel tables (64 pixels x 64 padded bins)
#pragma unroll 4
        for (int i = tid; i < CHUNK * HBP; i += 256) {
            int pi = i >> 6, bin = i & 63;
            float bval = -3.f + 0.1f * (float)bin;
            float ok = (bin < HB) ? 1.f : 0.f;
            float du = suu[pi] - bval;
            float dv = svv[pi] - bval;
            sku[pi][bin] = ok * sww[pi] * __expf(-du * du * inv_su2);
            skv[pi][bin] = ok * __expf(-dv * dv * inv_sv2);
        }
        __syncthreads();
        // phase 3: rank-1 outer-product accumulation, wave-uniform tail skip
        for (int pi = 0; pi < CHUNK; ++pi) {
            float u = suu[pi];
            if (u < wave_lo - Ru || u > wave_hi + Ru) continue;
            float4 a  = *(const float4*)&sku[pi][ub0];
            float4 bb = *(const float4*)&skv[pi][vb0];
            acc[0][0] = fmaf(a.x, bb.x, acc[0][0]);
            acc[0][1] = fmaf(a.x, bb.y, acc[0][1]);
            acc[0][2] = fmaf(a.x, bb.z, acc[0][2]);
            acc[0][3] = fmaf(a.x, bb.w, acc[0][3]);
            acc[1][0] = fmaf(a.y, bb.x, acc[1][0]);
            acc[1][1] = fmaf(a.y, bb.y, acc[1][1]);
            acc[1][2] = fmaf(a.y, bb.z, acc[1][2]);
            acc[1][3] = fmaf(a.y, bb.w, acc[1][3]);
            acc[2][0] = fmaf(a.z, bb.x, acc[2][0]);
            acc[2][1] = fmaf(a.z, bb.y, acc[2][1]);
            acc[2][2] = fmaf(a.z, bb.z, acc[2][2]);
            acc[2][3] = fmaf(a.z, bb.w, acc[2][3]);
            acc[3][0] = fmaf(a.w, bb.x, acc[3][0]);
            acc[3][1] = fmaf(a.w, bb.y, acc[3][1]);
            acc[3][2] = fmaf(a.w, bb.z, acc[3][2]);
            acc[3][3] = fmaf(a.w, bb.w, acc[3][3]);
        }
        __syncthreads();
    }

    float* hp = hist + (size_t)bc * HB * HB;
#pragma unroll
    for (int i = 0; i < 4; ++i) {
        int ub = ub0 + i;
        if (ub >= HB) continue;
#pragma unroll
        for (int j = 0; j < 4; ++j) {
            int vb = vb0 + j;
            if (vb >= HB) continue;
            atomicAdd(&hp[ub * HB + vb], acc[i][j]);
        }
    }
}

// ---------------------------------------------------------------------------
// Per-batch normalization: hist /= (sum + 1e-6).  grid 16, block 256.
// ---------------------------------------------------------------------------
__global__ __launch_bounds__(256) void norm_hist(float* __restrict__ hist)
{
    const int b = blockIdx.x;
    float* hp = hist + (size_t)b * 3 * HB * HB;
    const int N = 3 * HB * HB;
    float s = 0.f;
    for (int i = threadIdx.x; i < N; i += 256) s += hp[i];
    __shared__ float red[4];
    for (int off = 32; off; off >>= 1) s += __shfl_down(s, off, 64);
    if ((threadIdx.x & 63) == 0) red[threadIdx.x >> 6] = s;
    __syncthreads();
    float inv = 1.f / (red[0] + red[1] + red[2] + red[3] + 1e-6f);
    for (int i = threadIdx.x; i < N; i += 256) hp[i] *= inv;
}

// ---------------------------------------------------------------------------
// Direct conv + bias + ReLU, VALID padding.
// grid (B, COUT/CPB), block 256.  Input chunk of CCH channels staged in LDS,
// weights staged as [ci][kh][kw][co] for float4 broadcast reads.
// ---------------------------------------------------------------------------
template<int CIN, int COUT, int K, int S, int IN, int OUT, int CPB, int CCH, int NSP>
__global__ __launch_bounds__(256) void conv_relu(
    const float* __restrict__ in, const float* __restrict__ wt,
    const float* __restrict__ bias, float* __restrict__ out)
{
    constexpr int NCH = CIN / CCH;
    constexpr int OSZ = OUT * OUT;
    const int b = blockIdx.x;
    const int co0 = blockIdx.y * CPB;
    const int tid = threadIdx.x;

    __shared__ __align__(16) float sIn[CCH * IN * IN];
    __shared__ __align__(16) float sW[CCH * K * K * CPB];
    __shared__ float sB[CPB];
    if (tid < CPB) sB[tid] = bias[co0 + tid];

    float acc[NSP][CPB];
#pragma unroll
    for (int i = 0; i < NSP; ++i)
#pragma unroll
        for (int j = 0; j < CPB; ++j) acc[i][j] = 0.f;

    for (int ch = 0; ch < NCH; ++ch) {
        const float* gin = in + ((size_t)b * CIN + ch * CCH) * (IN * IN);
        for (int i = tid; i < CCH * IN * IN; i += 256) sIn[i] = gin[i];
        const float* gwt = wt + (size_t)co0 * CIN * K * K + (size_t)ch * CCH * K * K;
        for (int i = tid; i < CCH * K * K * CPB; i += 256) {
            int co = i % CPB;
            int r  = i / CPB;          // ci*K*K + kh*K + kw
            sW[i] = gwt[(size_t)co * CIN * K * K + r];
        }
        __syncthreads();
#pragma unroll
        for (int isp = 0; isp < NSP; ++isp) {
            int sp = tid + isp * 256;
            if (sp < OSZ) {
                int oh = sp / OUT, ow = sp % OUT;
                const float* ibase = &sIn[(oh * S) * IN + ow * S];
                for (int ci = 0; ci < CCH; ++ci) {
#pragma unroll
                    for (int kh = 0; kh < K; ++kh) {
#pragma unroll
                        for (int kw = 0; kw < K; ++kw) {
                            float x = ibase[ci * IN * IN + kh * IN + kw];
                            const float4* w4 =
                                (const float4*)&sW[(ci * K * K + kh * K + kw) * CPB];
#pragma unroll
                            for (int c4 = 0; c4 < CPB / 4; ++c4) {
                                float4 wv = w4[c4];
                                acc[isp][c4 * 4 + 0] = fmaf(x, wv.x, acc[isp][c4 * 4 + 0]);
                                acc[isp][c4 * 4 + 1] = fmaf(x, wv.y, acc[isp][c4 * 4 + 1]);
                                acc[isp][c4 * 4 + 2] = fmaf(x, wv.z, acc[isp][c4 * 4 + 2]);
                                acc[isp][c4 * 4 + 3] = fmaf(x, wv.w, acc[isp][c4 * 4 + 3]);
                            }
                        }
                    }
                }
            }
        }
        __syncthreads();
    }
#pragma unroll
    for (int isp = 0; isp < NSP; ++isp) {
        int sp = tid + isp * 256;
        if (sp < OSZ) {
            int oh = sp / OUT, ow = sp % OUT;
#pragma unroll
            for (int co = 0; co < CPB; ++co) {
                float y = acc[isp][co] + sB[co];
                out[(((size_t)b * COUT + co0 + co) * OUT + oh) * OUT + ow] = fmaxf(y, 0.f);
            }
        }
    }
}

// ---------------------------------------------------------------------------
// FC: out[b][o] = | z[b,:] . fcw[o,:] |.  grid (B, NOUT), block 256.
// ---------------------------------------------------------------------------
__global__ __launch_bounds__(256) void fc_abs(
    const float* __restrict__ z, const float* __restrict__ fcw,
    float* __restrict__ out, int Kdim)
{
    const int b = blockIdx.x, o = blockIdx.y;
    const float* zp = z + (size_t)b * Kdim;
    const float* wp = fcw + (size_t)o * Kdim;
    float s = 0.f;
    for (int k = threadIdx.x; k < Kdim; k += 256) s = fmaf(zp[k], wp[k], s);
    __shared__ float red[4];
    for (int off = 32; off; off >>= 1) s += __shfl_down(s, off, 64);
    if ((threadIdx.x & 63) == 0) red[threadIdx.x >> 6] = s;
    __syncthreads();
    if (threadIdx.x == 0)
        out[(size_t)b * gridDim.y + o] = fabsf(red[0] + red[1] + red[2] + red[3]);
}

// ---------------------------------------------------------------------------
// m = reshape(h,3,3)^T; n = max L1 row norm + 1e-4; msc = m / n.
// ---------------------------------------------------------------------------
__global__ void build_m(const float* __restrict__ h, float* __restrict__ msc)
{
    int b = threadIdx.x;
    if (b < 16) {
        float m[9];
#pragma unroll
        for (int i = 0; i < 3; ++i)
#pragma unroll
            for (int j = 0; j < 3; ++j) m[i * 3 + j] = h[b * 9 + j * 3 + i];
        float n = 0.f;
#pragma unroll
        for (int i = 0; i < 3; ++i) {
            float r = fabsf(m[i * 3]) + fabsf(m[i * 3 + 1]) + fabsf(m[i * 3 + 2]);
            n = fmaxf(n, r);
        }
        n += 1e-4f;
        float inv = 1.f / n;
#pragma unroll
        for (int k = 0; k < 9; ++k) msc[b * 9 + k] = m[k] * inv;
    }
}

// ---------------------------------------------------------------------------
// est[b] = inv(msc[b]) @ ill[b]
// ---------------------------------------------------------------------------
__global__ void final_est(const float* __restrict__ msc, const float* __restrict__ ill,
                          float* __restrict__ out)
{
    int bidx = threadIdx.x;
    if (bidx < 16) {
        const float* m = msc + bidx * 9;
        float a = m[0], b = m[1], c = m[2];
        float d = m[3], e = m[4], f = m[5];
        float g = m[6], h = m[7], i = m[8];
        float A = e * i - f * h, B = f * g - d * i, C = d * h - e * g;
        float D = c * h - b * i, E = a * i - c * g, F = b * g - a * h;
        float G = b * f - c * e, H = c * d - a * f, I = a * e - b * d;
        float det = a * A + b * B + c * C;
        float inv_det = 1.f / det;
        float x0 = ill[bidx * 3 + 0], x1 = ill[bidx * 3 + 1], x2 = ill[bidx * 3 + 2];
        out[bidx * 3 + 0] = (A * x0 + D * x1 + G * x2) * inv_det;
        out[bidx * 3 + 1] = (B * x0 + E * x1 + H * x2) * inv_det;
        out[bidx * 3 + 2] = (C * x0 + F * x1 + I * x2) * inv_det;
    }
}

extern "C" void kernel_launch(void* const* d_in, const int* in_sizes, int n_in,
                              void* d_out, int out_size, void* d_ws, size_t ws_size,
                              hipStream_t stream)
{
    (void)in_sizes; (void)n_in; (void)out_size; (void)ws_size;
    const float* image = (const float*)d_in[0];
    const float* su_s  = (const float*)d_in[1];
    const float* sv_s  = (const float*)d_in[2];
    const float* c_s   = (const float*)d_in[3];
    const float* w1_s  = (const float*)d_in[4];
    const float* b1_s  = (const float*)d_in[5];
    const float* w2_s  = (const float*)d_in[6];
    const float* b2_s  = (const float*)d_in[7];
    const float* w3_s  = (const float*)d_in[8];
    const float* b3_s  = (const float*)d_in[9];
    const float* fc_s  = (const float*)d_in[10];
    const float* su_i  = (const float*)d_in[11];
    const float* sv_i  = (const float*)d_in[12];
    const float* c_i   = (const float*)d_in[13];
    const float* w1_i  = (const float*)d_in[14];
    const float* b1_i  = (const float*)d_in[15];
    const float* w2_i  = (const float*)d_in[16];
    const float* w3b_i = (const float*)d_in[17];  // b2_i
    const float* w3_i  = (const float*)d_in[18];
    const float* b3_i  = (const float*)d_in[19];
    const float* fc_i  = (const float*)d_in[20];
    const float* b2_i  = w3b_i;

    float* W    = (float*)d_ws;
    float* hist = W;                              // 16*3*61*61   = 178608
    float* o1   = hist + 178608;                  // 16*128*29*29 = 1722368
    float* o2   = o1 + 1722368;                   // 16*256*14*14 = 802816
    float* o3   = o2 + 802816;                    // 16*512*13*13 = 1384448
    float* hd   = o3 + 1384448;                   // 16*9 head output
    float* msc  = hd + 144;                       // 16*9 scaled matrix

    const size_t HIST_BYTES = 178608u * sizeof(float);
    const int FCK = 512 * 13 * 13;

    // ---- sensor branch ----
    hipMemsetAsync(hist, 0, HIST_BYTES, stream);
    hist_kernel<<<dim3(48, HSPLIT), 256, 0, stream>>>(image, su_s, sv_s, c_s, nullptr, hist);
    norm_hist<<<16, 256, 0, stream>>>(hist);
    conv_relu<3, 128, 5, 2, 61, 29, 16, 3, 4><<<dim3(16, 8), 256, 0, stream>>>(hist, w1_s, b1_s, o1);
    conv_relu<128, 256, 3, 2, 29, 14, 16, 16, 1><<<dim3(16, 16), 256, 0, stream>>>(o1, w2_s, b2_s, o2);
    conv_relu<256, 512, 2, 1, 14, 13, 16, 32, 1><<<dim3(16, 32), 256, 0, stream>>>(o2, w3_s, b3_s, o3);
    fc_abs<<<dim3(16, 9), 256, 0, stream>>>(o3, fc_s, hd, FCK);
    build_m<<<1, 64, 0, stream>>>(hd, msc);

    // ---- illuminant branch (on color-mapped image) ----
    hipMemsetAsync(hist, 0, HIST_BYTES, stream);
    hist_kernel<<<dim3(48, HSPLIT), 256, 0, stream>>>(image, su_i, sv_i, c_i, msc, hist);
    norm_hist<<<16, 256, 0, stream>>>(hist);
    conv_relu<3, 128, 5, 2, 61, 29, 16, 3, 4><<<dim3(16, 8), 256, 0, stream>>>(hist, w1_i, b1_i, o1);
    conv_relu<128, 256, 3, 2, 29, 14, 16, 16, 1><<<dim3(16, 16), 256, 0, stream>>>(o1, w2_i, b2_i, o2);
    conv_relu<256, 512, 2, 1, 14, 13, 16, 32, 1><<<dim3(16, 32), 256, 0, stream>>>(o2, w3_i, b3_i, o3);
    fc_abs<<<dim3(16, 3), 256, 0, stream>>>(o3, fc_i, hd, FCK);
    final_est<<<1, 64, 0, stream>>>(msc, hd, (float*)d_out);
}

// Round 3
// 945.056 us; speedup vs baseline: 1.5396x; 1.5396x over previous
//
#include <hip/hip_runtime.h>

#define P_PIX 22500
#define HB 61
#define HBP 64
#define CHUNK 64
#define HSPLIT 32

// ---------------------------------------------------------------------------
// RGB-uv soft histogram.  grid (48 = B*3, HSPLIT), block 256.
// Each block: one (b, c) pair, 1/HSPLIT of the pixels.
// Wave w owns u-bins [16w, 16w+16); thread tile = 4x4 bins; atomicAdd epilogue.
// Optional 3x3 color transform msc (illuminant branch maps pixels first).
// ---------------------------------------------------------------------------
__global__ __launch_bounds__(256) void hist_kernel(
    const float* __restrict__ img, const float* __restrict__ su,
    const float* __restrict__ sv, const float* __restrict__ cw,
    const float* __restrict__ msc, float* __restrict__ hist)
{
    const int bc = blockIdx.x;
    const int b = bc / 3, c = bc % 3;
    const int split = blockIdx.y;
    const int tid = threadIdx.x;

    __shared__ __align__(16) float sku[CHUNK][HBP];   // w * exp(-(u-bin)^2/su^2)
    __shared__ __align__(16) float skv[CHUNK][HBP];   // exp(-(v-bin)^2/sv^2)
    __shared__ float suu[CHUNK], svv[CHUNK], sww[CHUNK];

    const float sig_u = su[c], sig_v = sv[c];
    const float inv_su2 = 1.f / (sig_u * sig_u);
    const float inv_sv2 = 1.f / (sig_v * sig_v);
    const float cwc = cw[c];
    const float Ru = 4.6f * sig_u;   // exp(-21.2) ~ 6e-10 tail cutoff

    const bool hasM = (msc != nullptr);
    float m00=0,m01=0,m02=0,m10=0,m11=0,m12=0,m20=0,m21=0,m22=0;
    if (hasM) {
        const float* mp = msc + b * 9;
        m00=mp[0]; m01=mp[1]; m02=mp[2];
        m10=mp[3]; m11=mp[4]; m12=mp[5];
        m20=mp[6]; m21=mp[7]; m22=mp[8];
    }

    const int w    = tid >> 6;         // wave id 0..3 -> u-bin group [16w,16w+16)
    const int usub = tid & 3;          // 4 u-bins within the wave's group
    const int tv   = (tid >> 2) & 15;  // v tile
    const int ub0  = w * 16 + usub * 4;
    const int vb0  = tv * 4;
    const float wave_lo = -3.f + 0.1f * (float)(w * 16);
    const float wave_hi = wave_lo + 1.5f;

    float acc[4][4];
#pragma unroll
    for (int i = 0; i < 4; ++i)
#pragma unroll
        for (int j = 0; j < 4; ++j) acc[i][j] = 0.f;

    for (int base = split * CHUNK; base < P_PIX; base += HSPLIT * CHUNK) {
        // phase 1: u, v, weight for 64 pixels
        if (tid < CHUNK) {
            int pp = base + tid;
            float u = 0.f, v = 0.f, wgt = 0.f;
            if (pp < P_PIX) {
                const float* ip = img + (size_t)b * 3 * P_PIX + pp;
                float r = ip[0], g = ip[P_PIX], bl = ip[2 * P_PIX];
                if (hasM) {
                    float r2 = m00 * r + m01 * g + m02 * bl;
                    float g2 = m10 * r + m11 * g + m12 * bl;
                    float b2 = m20 * r + m21 * g + m22 * bl;
                    r = r2; g = g2; bl = b2;
                }
                r  = fminf(fmaxf(r, 0.f), 1.f);
                g  = fminf(fmaxf(g, 0.f), 1.f);
                bl = fminf(fmaxf(bl, 0.f), 1.f);
                float Iy = sqrtf(r * r + g * g + bl * bl);
                float lr = __logf(r + 1e-6f);
                float lg = __logf(g + 1e-6f);
                float lb = __logf(bl + 1e-6f);
                if (c == 0)      { u = lr - lg; v = lr - lb; }
                else if (c == 1) { u = lg - lr; v = lg - lb; }
                else             { u = lb - lr; v = lb - lg; }
                wgt = Iy * cwc;
            }
            suu[tid] = u; svv[tid] = v; sww[tid] = wgt;
        }
        __syncthreads();
        // phase 2: Gaussian kernel tables (64 pixels x 64 padded bins)
#pragma unroll 4
        for (int i = tid; i < CHUNK * HBP; i += 256) {
            int pi = i >> 6, bin = i & 63;
            float bval = -3.f + 0.1f * (float)bin;
            float ok = (bin < HB) ? 1.f : 0.f;
            float du = suu[pi] - bval;
            float dv = svv[pi] - bval;
            sku[pi][bin] = ok * sww[pi] * __expf(-du * du * inv_su2);
            skv[pi][bin] = ok * __expf(-dv * dv * inv_sv2);
        }
        __syncthreads();
        // phase 3: rank-1 outer-product accumulation, wave-uniform tail skip
        for (int pi = 0; pi < CHUNK; ++pi) {
            float u = suu[pi];
            if (u < wave_lo - Ru || u > wave_hi + Ru) continue;
            float4 a  = *(const float4*)&sku[pi][ub0];
            float4 bb = *(const float4*)&skv[pi][vb0];
            acc[0][0] = fmaf(a.x, bb.x, acc[0][0]);
            acc[0][1] = fmaf(a.x, bb.y, acc[0][1]);
            acc[0][2] = fmaf(a.x, bb.z, acc[0][2]);
            acc[0][3] = fmaf(a.x, bb.w, acc[0][3]);
            acc[1][0] = fmaf(a.y, bb.x, acc[1][0]);
            acc[1][1] = fmaf(a.y, bb.y, acc[1][1]);
            acc[1][2] = fmaf(a.y, bb.z, acc[1][2]);
            acc[1][3] = fmaf(a.y, bb.w, acc[1][3]);
            acc[2][0] = fmaf(a.z, bb.x, acc[2][0]);
            acc[2][1] = fmaf(a.z, bb.y, acc[2][1]);
            acc[2][2] = fmaf(a.z, bb.z, acc[2][2]);
            acc[2][3] = fmaf(a.z, bb.w, acc[2][3]);
            acc[3][0] = fmaf(a.w, bb.x, acc[3][0]);
            acc[3][1] = fmaf(a.w, bb.y, acc[3][1]);
            acc[3][2] = fmaf(a.w, bb.z, acc[3][2]);
            acc[3][3] = fmaf(a.w, bb.w, acc[3][3]);
        }
        __syncthreads();
    }

    float* hp = hist + (size_t)bc * HB * HB;
#pragma unroll
    for (int i = 0; i < 4; ++i) {
        int ub = ub0 + i;
        if (ub >= HB) continue;
#pragma unroll
        for (int j = 0; j < 4; ++j) {
            int vb = vb0 + j;
            if (vb >= HB) continue;
            atomicAdd(&hp[ub * HB + vb], acc[i][j]);
        }
    }
}

// ---------------------------------------------------------------------------
// Per-batch normalization: hist /= (sum + 1e-6).  grid 16, block 256.
// ---------------------------------------------------------------------------
__global__ __launch_bounds__(256) void norm_hist(float* __restrict__ hist)
{
    const int b = blockIdx.x;
    float* hp = hist + (size_t)b * 3 * HB * HB;
    const int N = 3 * HB * HB;
    float s = 0.f;
    for (int i = threadIdx.x; i < N; i += 256) s += hp[i];
    __shared__ float red[4];
    for (int off = 32; off; off >>= 1) s += __shfl_down(s, off, 64);
    if ((threadIdx.x & 63) == 0) red[threadIdx.x >> 6] = s;
    __syncthreads();
    float inv = 1.f / (red[0] + red[1] + red[2] + red[3] + 1e-6f);
    for (int i = threadIdx.x; i < N; i += 256) hp[i] *= inv;
}

// ---------------------------------------------------------------------------
// conv1 only: direct conv + bias + ReLU (small, CIN=3).
// ---------------------------------------------------------------------------
template<int CIN, int COUT, int K, int S, int IN, int OUT, int CPB, int CCH, int NSP>
__global__ __launch_bounds__(256) void conv_relu(
    const float* __restrict__ in, const float* __restrict__ wt,
    const float* __restrict__ bias, float* __restrict__ out)
{
    constexpr int NCH = CIN / CCH;
    constexpr int OSZ = OUT * OUT;
    const int b = blockIdx.x;
    const int co0 = blockIdx.y * CPB;
    const int tid = threadIdx.x;

    __shared__ __align__(16) float sIn[CCH * IN * IN];
    __shared__ __align__(16) float sW[CCH * K * K * CPB];
    __shared__ float sB[CPB];
    if (tid < CPB) sB[tid] = bias[co0 + tid];

    float acc[NSP][CPB];
#pragma unroll
    for (int i = 0; i < NSP; ++i)
#pragma unroll
        for (int j = 0; j < CPB; ++j) acc[i][j] = 0.f;

    for (int ch = 0; ch < NCH; ++ch) {
        const float* gin = in + ((size_t)b * CIN + ch * CCH) * (IN * IN);
        for (int i = tid; i < CCH * IN * IN; i += 256) sIn[i] = gin[i];
        const float* gwt = wt + (size_t)co0 * CIN * K * K + (size_t)ch * CCH * K * K;
        for (int i = tid; i < CCH * K * K * CPB; i += 256) {
            int co = i % CPB;
            int r  = i / CPB;          // ci*K*K + kh*K + kw
            sW[i] = gwt[(size_t)co * CIN * K * K + r];
        }
        __syncthreads();
#pragma unroll
        for (int isp = 0; isp < NSP; ++isp) {
            int sp = tid + isp * 256;
            if (sp < OSZ) {
                int oh = sp / OUT, ow = sp % OUT;
                const float* ibase = &sIn[(oh * S) * IN + ow * S];
                for (int ci = 0; ci < CCH; ++ci) {
#pragma unroll
                    for (int kh = 0; kh < K; ++kh) {
#pragma unroll
                        for (int kw = 0; kw < K; ++kw) {
                            float x = ibase[ci * IN * IN + kh * IN + kw];
                            const float4* w4 =
                                (const float4*)&sW[(ci * K * K + kh * K + kw) * CPB];
#pragma unroll
                            for (int c4 = 0; c4 < CPB / 4; ++c4) {
                                float4 wv = w4[c4];
                                acc[isp][c4 * 4 + 0] = fmaf(x, wv.x, acc[isp][c4 * 4 + 0]);
                                acc[isp][c4 * 4 + 1] = fmaf(x, wv.y, acc[isp][c4 * 4 + 1]);
                                acc[isp][c4 * 4 + 2] = fmaf(x, wv.z, acc[isp][c4 * 4 + 2]);
                                acc[isp][c4 * 4 + 3] = fmaf(x, wv.w, acc[isp][c4 * 4 + 3]);
                            }
                        }
                    }
                }
            }
        }
        __syncthreads();
    }
#pragma unroll
    for (int isp = 0; isp < NSP; ++isp) {
        int sp = tid + isp * 256;
        if (sp < OSZ) {
            int oh = sp / OUT, ow = sp % OUT;
#pragma unroll
            for (int co = 0; co < CPB; ++co) {
                float y = acc[isp][co] + sB[co];
                out[(((size_t)b * COUT + co0 + co) * OUT + oh) * OUT + ow] = fmaxf(y, 0.f);
            }
        }
    }
}

// ---------------------------------------------------------------------------
// conv2/conv3: split-K direct conv, register tile NSP spatial x NCO co.
// grid (B, COUT/CPB, KSPL), block 256 = 4 co-groups x 64 spatial-groups.
// Output accumulated with global fp32 atomics (pre-zeroed); bias+ReLU later.
// ---------------------------------------------------------------------------
template<int CIN, int COUT, int K, int S, int IN, int OUT, int CPB, int NCO,
         int NSP, int CCH, int KSPL>
__global__ __launch_bounds__(256) void conv_split(
    const float* __restrict__ in, const float* __restrict__ wt,
    float* __restrict__ out)
{
    constexpr int KK = K * K;
    constexpr int CI_SPL = CIN / KSPL;
    constexpr int NCH = CI_SPL / CCH;
    constexpr int OSZ = OUT * OUT;
    const int b = blockIdx.x;
    const int co0 = blockIdx.y * CPB;
    const int ci_base = blockIdx.z * CI_SPL;
    const int tid = threadIdx.x;
    const int co_grp = tid >> 6;      // 0..3 -> co sub-range of NCO
    const int sp_grp = tid & 63;

    __shared__ __align__(16) float sIn[CCH * IN * IN];
    __shared__ __align__(16) float sW[CCH * KK * CPB];

    int off[NSP];
    bool act[NSP];
#pragma unroll
    for (int i = 0; i < NSP; ++i) {
        int sp = sp_grp + 64 * i;
        act[i] = (sp < OSZ);
        int oh = act[i] ? sp / OUT : 0;
        int ow = act[i] ? sp % OUT : 0;
        off[i] = oh * S * IN + ow * S;
    }

    float acc[NSP][NCO];
#pragma unroll
    for (int i = 0; i < NSP; ++i)
#pragma unroll
        for (int j = 0; j < NCO; ++j) acc[i][j] = 0.f;

    for (int ch = 0; ch < NCH; ++ch) {
        const int ci0 = ci_base + ch * CCH;
        const float* gin = in + ((size_t)b * CIN + ci0) * (IN * IN);
        for (int i = tid; i < CCH * IN * IN; i += 256) sIn[i] = gin[i];
        const float* gwt = wt + (size_t)co0 * CIN * KK + (size_t)ci0 * KK;
        for (int i = tid; i < CCH * KK * CPB; i += 256) {
            int co = i % CPB;
            int r  = i / CPB;
            sW[i] = gwt[(size_t)co * CIN * KK + r];
        }
        __syncthreads();
        for (int ci = 0; ci < CCH; ++ci) {
#pragma unroll
            for (int kh = 0; kh < K; ++kh) {
#pragma unroll
                for (int kw = 0; kw < K; ++kw) {
                    float x[NSP];
#pragma unroll
                    for (int i = 0; i < NSP; ++i)
                        x[i] = sIn[ci * IN * IN + kh * IN + kw + off[i]];
                    const float4* w4 =
                        (const float4*)&sW[((ci * K + kh) * K + kw) * CPB + co_grp * NCO];
#pragma unroll
                    for (int c4 = 0; c4 < NCO / 4; ++c4) {
                        float4 wv = w4[c4];
#pragma unroll
                        for (int i = 0; i < NSP; ++i) {
                            acc[i][c4 * 4 + 0] = fmaf(x[i], wv.x, acc[i][c4 * 4 + 0]);
                            acc[i][c4 * 4 + 1] = fmaf(x[i], wv.y, acc[i][c4 * 4 + 1]);
                            acc[i][c4 * 4 + 2] = fmaf(x[i], wv.z, acc[i][c4 * 4 + 2]);
                            acc[i][c4 * 4 + 3] = fmaf(x[i], wv.w, acc[i][c4 * 4 + 3]);
                        }
                    }
                }
            }
        }
        __syncthreads();
    }

#pragma unroll
    for (int i = 0; i < NSP; ++i) {
        if (!act[i]) continue;
        int sp = sp_grp + 64 * i;
#pragma unroll
        for (int j = 0; j < NCO; ++j) {
            int co = co0 + co_grp * NCO + j;
            atomicAdd(&out[((size_t)b * COUT + co) * OSZ + sp], acc[i][j]);
        }
    }
}

// ---------------------------------------------------------------------------
// bias + ReLU over a [B, COUT, OSZ] tensor (after split-K accumulation).
// ---------------------------------------------------------------------------
__global__ __launch_bounds__(256) void bias_relu(
    float* __restrict__ x, const float* __restrict__ bias,
    int cout, int osz, int total)
{
    for (int i = blockIdx.x * 256 + threadIdx.x; i < total; i += gridDim.x * 256) {
        int co = (i / osz) % cout;
        x[i] = fmaxf(x[i] + bias[co], 0.f);
    }
}

// ---------------------------------------------------------------------------
// FC split-K: partial dot -> atomicAdd into out[b*NO+o] (pre-zeroed).
// grid (B, NO, KSPL), block 256.  abs() applied by consumers.
// ---------------------------------------------------------------------------
__global__ __launch_bounds__(256) void fc_atomic(
    const float* __restrict__ z, const float* __restrict__ fcw,
    float* __restrict__ out, int Kdim, int NO, int KSPL)
{
    const int b = blockIdx.x, o = blockIdx.y, ks = blockIdx.z;
    const int kchunk = Kdim / KSPL;
    const int k0 = ks * kchunk;
    const float* zp = z + (size_t)b * Kdim + k0;
    const float* wp = fcw + (size_t)o * Kdim + k0;
    float s = 0.f;
    for (int k = threadIdx.x; k < kchunk; k += 256) s = fmaf(zp[k], wp[k], s);
    __shared__ float red[4];
    for (int off = 32; off; off >>= 1) s += __shfl_down(s, off, 64);
    if ((threadIdx.x & 63) == 0) red[threadIdx.x >> 6] = s;
    __syncthreads();
    if (threadIdx.x == 0)
        atomicAdd(&out[(size_t)b * NO + o], red[0] + red[1] + red[2] + red[3]);
}

// ---------------------------------------------------------------------------
// m = reshape(|h|,3,3)^T; n = max L1 row norm + 1e-4; msc = m / n.
// ---------------------------------------------------------------------------
__global__ void build_m(const float* __restrict__ h, float* __restrict__ msc)
{
    int b = threadIdx.x;
    if (b < 16) {
        float m[9];
#pragma unroll
        for (int i = 0; i < 3; ++i)
#pragma unroll
            for (int j = 0; j < 3; ++j) m[i * 3 + j] = fabsf(h[b * 9 + j * 3 + i]);
        float n = 0.f;
#pragma unroll
        for (int i = 0; i < 3; ++i) {
            float r = m[i * 3] + m[i * 3 + 1] + m[i * 3 + 2];
            n = fmaxf(n, r);
        }
        n += 1e-4f;
        float inv = 1.f / n;
#pragma unroll
        for (int k = 0; k < 9; ++k) msc[b * 9 + k] = m[k] * inv;
    }
}

// ---------------------------------------------------------------------------
// est[b] = inv(msc[b]) @ |ill[b]|
// ---------------------------------------------------------------------------
__global__ void final_est(const float* __restrict__ msc, const float* __restrict__ ill,
                          float* __restrict__ out)
{
    int bidx = threadIdx.x;
    if (bidx < 16) {
        const float* m = msc + bidx * 9;
        float a = m[0], b = m[1], c = m[2];
        float d = m[3], e = m[4], f = m[5];
        float g = m[6], h = m[7], i = m[8];
        float A = e * i - f * h, B = f * g - d * i, C = d * h - e * g;
        float D = c * h - b * i, E = a * i - c * g, F = b * g - a * h;
        float G = b * f - c * e, H = c * d - a * f, I = a * e - b * d;
        float det = a * A + b * B + c * C;
        float inv_det = 1.f / det;
        float x0 = fabsf(ill[bidx * 3 + 0]);
        float x1 = fabsf(ill[bidx * 3 + 1]);
        float x2 = fabsf(ill[bidx * 3 + 2]);
        out[bidx * 3 + 0] = (A * x0 + D * x1 + G * x2) * inv_det;
        out[bidx * 3 + 1] = (B * x0 + E * x1 + H * x2) * inv_det;
        out[bidx * 3 + 2] = (C * x0 + F * x1 + I * x2) * inv_det;
    }
}

extern "C" void kernel_launch(void* const* d_in, const int* in_sizes, int n_in,
                              void* d_out, int out_size, void* d_ws, size_t ws_size,
                              hipStream_t stream)
{
    (void)in_sizes; (void)n_in; (void)out_size; (void)ws_size;
    const float* image = (const float*)d_in[0];
    const float* su_s  = (const float*)d_in[1];
    const float* sv_s  = (const float*)d_in[2];
    const float* c_s   = (const float*)d_in[3];
    const float* w1_s  = (const float*)d_in[4];
    const float* b1_s  = (const float*)d_in[5];
    const float* w2_s  = (const float*)d_in[6];
    const float* b2_s  = (const float*)d_in[7];
    const float* w3_s  = (const float*)d_in[8];
    const float* b3_s  = (const float*)d_in[9];
    const float* fc_s  = (const float*)d_in[10];
    const float* su_i  = (const float*)d_in[11];
    const float* sv_i  = (const float*)d_in[12];
    const float* c_i   = (const float*)d_in[13];
    const float* w1_i  = (const float*)d_in[14];
    const float* b1_i  = (const float*)d_in[15];
    const float* w2_i  = (const float*)d_in[16];
    const float* b2_i  = (const float*)d_in[17];
    const float* w3_i  = (const float*)d_in[18];
    const float* b3_i  = (const float*)d_in[19];
    const float* fc_i  = (const float*)d_in[20];

    float* W    = (float*)d_ws;
    float* hist = W;                              // 16*3*61*61   = 178608
    float* o1   = hist + 178608;                  // 16*128*29*29 = 1722368
    float* o2   = o1 + 1722368;                   // 16*256*14*14 = 802816
    float* o3   = o2 + 802816;                    // 16*512*13*13 = 1384448
    float* hd   = o3 + 1384448;                   // 16*9 head output
    float* msc  = hd + 144;                       // 16*9 scaled matrix

    const size_t HIST_BYTES = 178608u * sizeof(float);
    const int FCK = 512 * 13 * 13;
    const int O2_TOT = 16 * 256 * 196;
    const int O3_TOT = 16 * 512 * 169;

    // ================= sensor branch =================
    hipMemsetAsync(hist, 0, HIST_BYTES, stream);
    hipMemsetAsync(o2, 0, (size_t)O2_TOT * 4, stream);
    hipMemsetAsync(o3, 0, (size_t)O3_TOT * 4, stream);
    hipMemsetAsync(hd, 0, 144 * 4, stream);
    hist_kernel<<<dim3(48, HSPLIT), 256, 0, stream>>>(image, su_s, sv_s, c_s, nullptr, hist);
    norm_hist<<<16, 256, 0, stream>>>(hist);
    conv_relu<3, 128, 5, 2, 61, 29, 16, 3, 4><<<dim3(16, 8), 256, 0, stream>>>(hist, w1_s, b1_s, o1);
    conv_split<128, 256, 3, 2, 29, 14, 64, 16, 4, 8, 8><<<dim3(16, 4, 8), 256, 0, stream>>>(o1, w2_s, o2);
    bias_relu<<<1024, 256, 0, stream>>>(o2, b2_s, 256, 196, O2_TOT);
    conv_split<256, 512, 2, 1, 14, 13, 64, 16, 3, 16, 8><<<dim3(16, 8, 8), 256, 0, stream>>>(o2, w3_s, o3);
    bias_relu<<<1024, 256, 0, stream>>>(o3, b3_s, 512, 169, O3_TOT);
    fc_atomic<<<dim3(16, 9, 8), 256, 0, stream>>>(o3, fc_s, hd, FCK, 9, 8);
    build_m<<<1, 64, 0, stream>>>(hd, msc);

    // ================= illuminant branch =================
    hipMemsetAsync(hist, 0, HIST_BYTES, stream);
    hipMemsetAsync(o2, 0, (size_t)O2_TOT * 4, stream);
    hipMemsetAsync(o3, 0, (size_t)O3_TOT * 4, stream);
    hipMemsetAsync(hd, 0, 144 * 4, stream);
    hist_kernel<<<dim3(48, HSPLIT), 256, 0, stream>>>(image, su_i, sv_i, c_i, msc, hist);
    norm_hist<<<16, 256, 0, stream>>>(hist);
    conv_relu<3, 128, 5, 2, 61, 29, 16, 3, 4><<<dim3(16, 8), 256, 0, stream>>>(hist, w1_i, b1_i, o1);
    conv_split<128, 256, 3, 2, 29, 14, 64, 16, 4, 8, 8><<<dim3(16, 4, 8), 256, 0, stream>>>(o1, w2_i, o2);
    bias_relu<<<1024, 256, 0, stream>>>(o2, b2_i, 256, 196, O2_TOT);
    conv_split<256, 512, 2, 1, 14, 13, 64, 16, 3, 16, 8><<<dim3(16, 8, 8), 256, 0, stream>>>(o2, w3_i, o3);
    bias_relu<<<1024, 256, 0, stream>>>(o3, b3_i, 512, 169, O3_TOT);
    fc_atomic<<<dim3(16, 3, 8), 256, 0, stream>>>(o3, fc_i, hd, FCK, 3, 8);
    final_est<<<1, 64, 0, stream>>>(msc, hd, (float*)d_out);
}

// Round 4
// 587.868 us; speedup vs baseline: 2.4750x; 1.6076x over previous
//
#include <hip/hip_runtime.h>

#define P_PIX 22500
#define HB 61
#define HSP 16           // pixel splits for hist
#define PPB 1408         // pixels per hist block (HSP*PPB >= P_PIX)
#define NCHK 11          // 128-px chunks per hist block

typedef float f32x4 __attribute__((ext_vector_type(4)));
typedef short bf16x8 __attribute__((ext_vector_type(8)));

__device__ inline short f2bf(float x) {
    union { float f; unsigned u; } c; c.f = x;
    unsigned r = (c.u + 0x7FFFu + ((c.u >> 16) & 1u)) >> 16;
    return (short)r;
}

// ---------------------------------------------------------------------------
// MFMA RGB-uv soft histogram.  grid (48 = B*3, HSP), block 256.
// Per (b,c): hist[u,v] = sum_p (ku[p,u]*w[p]) * kv[p,v]  == GEMM M=N=64,K=P.
// bf16 A/B fragments generated in LDS per 128-px chunk; fp32 MFMA accumulate;
// one atomicAdd per (u,v) bin per block at the end.
// A-frag layout (16x16x32): lane holds A[m=lane&15][k=(lane>>4)*8+j].
// LDS addr collapses to (pg*64 + u)*8 + j  (pg = 8-px group in chunk).
// ---------------------------------------------------------------------------
__global__ __launch_bounds__(256) void hist_mfma(
    const float* __restrict__ img, const float* __restrict__ su,
    const float* __restrict__ sv, const float* __restrict__ cw,
    const float* __restrict__ msc, float* __restrict__ hist)
{
    const int bc = blockIdx.x;
    const int b = bc / 3, c = bc % 3;
    const int split = blockIdx.y;
    const int tid  = threadIdx.x;
    const int w    = tid >> 6;      // wave id -> owns u-strip [16w,16w+16)
    const int lane = tid & 63;
    const int quad = lane >> 4;
    const int mr   = lane & 15;

    __shared__ __align__(16) short A_lds[8192];   // 16 KB: [pg(16)][u(64)][j(8)]
    __shared__ __align__(16) short B_lds[8192];
    __shared__ float suu[128], svv[128], sww[128];

    const float sig_u = su[c], sig_v = sv[c];
    const float inv_su2 = 1.f / (sig_u * sig_u);
    const float inv_sv2 = 1.f / (sig_v * sig_v);
    const float cwc = cw[c];

    const bool hasM = (msc != nullptr);
    float m00=0,m01=0,m02=0,m10=0,m11=0,m12=0,m20=0,m21=0,m22=0;
    if (hasM) {
        const float* mp = msc + b * 9;
        m00=mp[0]; m01=mp[1]; m02=mp[2];
        m10=mp[3]; m11=mp[4]; m12=mp[5];
        m20=mp[6]; m21=mp[7]; m22=mp[8];
    }

    const int p0   = split * PPB;
    const int pend = min(p0 + PPB, P_PIX);

    f32x4 acc[4];
#pragma unroll
    for (int nt = 0; nt < 4; ++nt) acc[nt] = (f32x4){0.f, 0.f, 0.f, 0.f};

    for (int chunk = 0; chunk < NCHK; ++chunk) {
        __syncthreads();   // protect A/B from prior chunk's MFMA reads
        // ---- phase 1: (u, v, weight) for 128 pixels ----
        if (tid < 128) {
            int px = p0 + chunk * 128 + tid;
            float u = 0.f, v = 0.f, wgt = 0.f;
            if (px < pend) {
                const float* ip = img + (size_t)b * 3 * P_PIX + px;
                float r = ip[0], g = ip[P_PIX], bl = ip[2 * P_PIX];
                if (hasM) {
                    float r2 = m00 * r + m01 * g + m02 * bl;
                    float g2 = m10 * r + m11 * g + m12 * bl;
                    float b2 = m20 * r + m21 * g + m22 * bl;
                    r = r2; g = g2; bl = b2;
                }
                r  = fminf(fmaxf(r, 0.f), 1.f);
                g  = fminf(fmaxf(g, 0.f), 1.f);
                bl = fminf(fmaxf(bl, 0.f), 1.f);
                float Iy = sqrtf(r * r + g * g + bl * bl);
                float lr = __logf(r + 1e-6f);
                float lg = __logf(g + 1e-6f);
                float lb = __logf(bl + 1e-6f);
                if (c == 0)      { u = lr - lg; v = lr - lb; }
                else if (c == 1) { u = lg - lr; v = lg - lb; }
                else             { u = lb - lr; v = lb - lg; }
                wgt = Iy * cwc;
            }
            suu[tid] = u; svv[tid] = v; sww[tid] = wgt;
        }
        __syncthreads();
        // ---- phase 2: bf16 fragment tables ----
        // A: ku*w, B: kv.  thread -> (u = idx&63, pg = idx>>6); one b128 write.
#pragma unroll
        for (int r = 0; r < 4; ++r) {
            int idx = tid + 256 * r;
            int u  = idx & 63;
            int pg = idx >> 6;           // wave-uniform -> suu reads broadcast
            float ub = -3.f + 0.1f * (float)u;
            const float* up = &suu[pg * 8];
            const float* wp = &sww[pg * 8];
            bf16x8 av;
#pragma unroll
            for (int j = 0; j < 8; ++j) {
                float du = up[j] - ub;
                av[j] = f2bf(__expf(-du * du * inv_su2) * wp[j]);
            }
            *(bf16x8*)&A_lds[(pg * 64 + u) * 8] = av;
        }
#pragma unroll
        for (int r = 0; r < 4; ++r) {
            int idx = tid + 256 * r;
            int u  = idx & 63;
            int pg = idx >> 6;
            float ub = -3.f + 0.1f * (float)u;
            const float* vp = &svv[pg * 8];
            bf16x8 bv;
#pragma unroll
            for (int j = 0; j < 8; ++j) {
                float dv = vp[j] - ub;
                bv[j] = f2bf(__expf(-dv * dv * inv_sv2));
            }
            *(bf16x8*)&B_lds[(pg * 64 + u) * 8] = bv;
        }
        __syncthreads();
        // ---- phase 3: MFMA.  wave w: u-strip mt=w, all 4 v-tiles ----
#pragma unroll
        for (int kk = 0; kk < 4; ++kk) {
            int pgq = kk * 4 + quad;
            bf16x8 av = *(const bf16x8*)&A_lds[(pgq * 64 + w * 16 + mr) * 8];
#pragma unroll
            for (int nt = 0; nt < 4; ++nt) {
                bf16x8 bv = *(const bf16x8*)&B_lds[(pgq * 64 + nt * 16 + mr) * 8];
                acc[nt] = __builtin_amdgcn_mfma_f32_16x16x32_bf16(av, bv, acc[nt], 0, 0, 0);
            }
        }
    }

    // epilogue: D[row=(lane>>4)*4+r][col=lane&15] per tile
    float* hp = hist + (size_t)bc * HB * HB;
#pragma unroll
    for (int nt = 0; nt < 4; ++nt) {
        int v = nt * 16 + mr;
        if (v >= HB) continue;
#pragma unroll
        for (int r = 0; r < 4; ++r) {
            int u = w * 16 + quad * 4 + r;
            if (u < HB) atomicAdd(&hp[u * HB + v], acc[nt][r]);
        }
    }
}

// ---------------------------------------------------------------------------
// Per-batch normalization: hist /= (sum + 1e-6).  grid 16, block 256.
// ---------------------------------------------------------------------------
__global__ __launch_bounds__(256) void norm_hist(float* __restrict__ hist)
{
    const int b = blockIdx.x;
    float* hp = hist + (size_t)b * 3 * HB * HB;
    const int N = 3 * HB * HB;
    float s = 0.f;
    for (int i = threadIdx.x; i < N; i += 256) s += hp[i];
    __shared__ float red[4];
    for (int off = 32; off; off >>= 1) s += __shfl_down(s, off, 64);
    if ((threadIdx.x & 63) == 0) red[threadIdx.x >> 6] = s;
    __syncthreads();
    float inv = 1.f / (red[0] + red[1] + red[2] + red[3] + 1e-6f);
    for (int i = threadIdx.x; i < N; i += 256) hp[i] *= inv;
}

// ---------------------------------------------------------------------------
// conv1 only: direct conv + bias + ReLU (small, CIN=3).
// ---------------------------------------------------------------------------
template<int CIN, int COUT, int K, int S, int IN, int OUT, int CPB, int CCH, int NSP>
__global__ __launch_bounds__(256) void conv_relu(
    const float* __restrict__ in, const float* __restrict__ wt,
    const float* __restrict__ bias, float* __restrict__ out)
{
    constexpr int NCH = CIN / CCH;
    constexpr int OSZ = OUT * OUT;
    const int b = blockIdx.x;
    const int co0 = blockIdx.y * CPB;
    const int tid = threadIdx.x;

    __shared__ __align__(16) float sIn[CCH * IN * IN];
    __shared__ __align__(16) float sW[CCH * K * K * CPB];
    __shared__ float sB[CPB];
    if (tid < CPB) sB[tid] = bias[co0 + tid];

    float acc[NSP][CPB];
#pragma unroll
    for (int i = 0; i < NSP; ++i)
#pragma unroll
        for (int j = 0; j < CPB; ++j) acc[i][j] = 0.f;

    for (int ch = 0; ch < NCH; ++ch) {
        const float* gin = in + ((size_t)b * CIN + ch * CCH) * (IN * IN);
        for (int i = tid; i < CCH * IN * IN; i += 256) sIn[i] = gin[i];
        const float* gwt = wt + (size_t)co0 * CIN * K * K + (size_t)ch * CCH * K * K;
        for (int i = tid; i < CCH * K * K * CPB; i += 256) {
            int co = i % CPB;
            int r  = i / CPB;
            sW[i] = gwt[(size_t)co * CIN * K * K + r];
        }
        __syncthreads();
#pragma unroll
        for (int isp = 0; isp < NSP; ++isp) {
            int sp = tid + isp * 256;
            if (sp < OSZ) {
                int oh = sp / OUT, ow = sp % OUT;
                const float* ibase = &sIn[(oh * S) * IN + ow * S];
                for (int ci = 0; ci < CCH; ++ci) {
#pragma unroll
                    for (int kh = 0; kh < K; ++kh) {
#pragma unroll
                        for (int kw = 0; kw < K; ++kw) {
                            float x = ibase[ci * IN * IN + kh * IN + kw];
                            const float4* w4 =
                                (const float4*)&sW[(ci * K * K + kh * K + kw) * CPB];
#pragma unroll
                            for (int c4 = 0; c4 < CPB / 4; ++c4) {
                                float4 wv = w4[c4];
                                acc[isp][c4 * 4 + 0] = fmaf(x, wv.x, acc[isp][c4 * 4 + 0]);
                                acc[isp][c4 * 4 + 1] = fmaf(x, wv.y, acc[isp][c4 * 4 + 1]);
                                acc[isp][c4 * 4 + 2] = fmaf(x, wv.z, acc[isp][c4 * 4 + 2]);
                                acc[isp][c4 * 4 + 3] = fmaf(x, wv.w, acc[isp][c4 * 4 + 3]);
                            }
                        }
                    }
                }
            }
        }
        __syncthreads();
    }
#pragma unroll
    for (int isp = 0; isp < NSP; ++isp) {
        int sp = tid + isp * 256;
        if (sp < OSZ) {
            int oh = sp / OUT, ow = sp % OUT;
#pragma unroll
            for (int co = 0; co < CPB; ++co) {
                float y = acc[isp][co] + sB[co];
                out[(((size_t)b * COUT + co0 + co) * OUT + oh) * OUT + ow] = fmaxf(y, 0.f);
            }
        }
    }
}

// ---------------------------------------------------------------------------
// conv2/conv3: split-K direct conv, register tile NSP spatial x NCO co.
// grid (B, COUT/CPB, KSPL), block 256 = 4 co-groups x 64 spatial-groups.
// Output accumulated with global fp32 atomics (pre-zeroed); bias+ReLU later.
// ---------------------------------------------------------------------------
template<int CIN, int COUT, int K, int S, int IN, int OUT, int CPB, int NCO,
         int NSP, int CCH, int KSPL>
__global__ __launch_bounds__(256) void conv_split(
    const float* __restrict__ in, const float* __restrict__ wt,
    float* __restrict__ out)
{
    constexpr int KK = K * K;
    constexpr int CI_SPL = CIN / KSPL;
    constexpr int NCH = CI_SPL / CCH;
    constexpr int OSZ = OUT * OUT;
    const int b = blockIdx.x;
    const int co0 = blockIdx.y * CPB;
    const int ci_base = blockIdx.z * CI_SPL;
    const int tid = threadIdx.x;
    const int co_grp = tid >> 6;
    const int sp_grp = tid & 63;

    __shared__ __align__(16) float sIn[CCH * IN * IN];
    __shared__ __align__(16) float sW[CCH * KK * CPB];

    int off[NSP];
    bool act[NSP];
#pragma unroll
    for (int i = 0; i < NSP; ++i) {
        int sp = sp_grp + 64 * i;
        act[i] = (sp < OSZ);
        int oh = act[i] ? sp / OUT : 0;
        int ow = act[i] ? sp % OUT : 0;
        off[i] = oh * S * IN + ow * S;
    }

    float acc[NSP][NCO];
#pragma unroll
    for (int i = 0; i < NSP; ++i)
#pragma unroll
        for (int j = 0; j < NCO; ++j) acc[i][j] = 0.f;

    for (int ch = 0; ch < NCH; ++ch) {
        const int ci0 = ci_base + ch * CCH;
        const float* gin = in + ((size_t)b * CIN + ci0) * (IN * IN);
        for (int i = tid; i < CCH * IN * IN; i += 256) sIn[i] = gin[i];
        const float* gwt = wt + (size_t)co0 * CIN * KK + (size_t)ci0 * KK;
        for (int i = tid; i < CCH * KK * CPB; i += 256) {
            int co = i % CPB;
            int r  = i / CPB;
            sW[i] = gwt[(size_t)co * CIN * KK + r];
        }
        __syncthreads();
        for (int ci = 0; ci < CCH; ++ci) {
#pragma unroll
            for (int kh = 0; kh < K; ++kh) {
#pragma unroll
                for (int kw = 0; kw < K; ++kw) {
                    float x[NSP];
#pragma unroll
                    for (int i = 0; i < NSP; ++i)
                        x[i] = sIn[ci * IN * IN + kh * IN + kw + off[i]];
                    const float4* w4 =
                        (const float4*)&sW[((ci * K + kh) * K + kw) * CPB + co_grp * NCO];
#pragma unroll
                    for (int c4 = 0; c4 < NCO / 4; ++c4) {
                        float4 wv = w4[c4];
#pragma unroll
                        for (int i = 0; i < NSP; ++i) {
                            acc[i][c4 * 4 + 0] = fmaf(x[i], wv.x, acc[i][c4 * 4 + 0]);
                            acc[i][c4 * 4 + 1] = fmaf(x[i], wv.y, acc[i][c4 * 4 + 1]);
                            acc[i][c4 * 4 + 2] = fmaf(x[i], wv.z, acc[i][c4 * 4 + 2]);
                            acc[i][c4 * 4 + 3] = fmaf(x[i], wv.w, acc[i][c4 * 4 + 3]);
                        }
                    }
                }
            }
        }
        __syncthreads();
    }

#pragma unroll
    for (int i = 0; i < NSP; ++i) {
        if (!act[i]) continue;
        int sp = sp_grp + 64 * i;
#pragma unroll
        for (int j = 0; j < NCO; ++j) {
            int co = co0 + co_grp * NCO + j;
            atomicAdd(&out[((size_t)b * COUT + co) * OSZ + sp], acc[i][j]);
        }
    }
}

// ---------------------------------------------------------------------------
// bias + ReLU over a [B, COUT, OSZ] tensor (after split-K accumulation).
// ---------------------------------------------------------------------------
__global__ __launch_bounds__(256) void bias_relu(
    float* __restrict__ x, const float* __restrict__ bias,
    int cout, int osz, int total)
{
    for (int i = blockIdx.x * 256 + threadIdx.x; i < total; i += gridDim.x * 256) {
        int co = (i / osz) % cout;
        x[i] = fmaxf(x[i] + bias[co], 0.f);
    }
}

// ---------------------------------------------------------------------------
// FC split-K: partial dot -> atomicAdd into out[b*NO+o] (pre-zeroed).
// ---------------------------------------------------------------------------
__global__ __launch_bounds__(256) void fc_atomic(
    const float* __restrict__ z, const float* __restrict__ fcw,
    float* __restrict__ out, int Kdim, int NO, int KSPL)
{
    const int b = blockIdx.x, o = blockIdx.y, ks = blockIdx.z;
    const int kchunk = Kdim / KSPL;
    const int k0 = ks * kchunk;
    const float* zp = z + (size_t)b * Kdim + k0;
    const float* wp = fcw + (size_t)o * Kdim + k0;
    float s = 0.f;
    for (int k = threadIdx.x; k < kchunk; k += 256) s = fmaf(zp[k], wp[k], s);
    __shared__ float red[4];
    for (int off = 32; off; off >>= 1) s += __shfl_down(s, off, 64);
    if ((threadIdx.x & 63) == 0) red[threadIdx.x >> 6] = s;
    __syncthreads();
    if (threadIdx.x == 0)
        atomicAdd(&out[(size_t)b * NO + o], red[0] + red[1] + red[2] + red[3]);
}

// ---------------------------------------------------------------------------
// m = reshape(|h|,3,3)^T; n = max L1 row norm + 1e-4; msc = m / n.
// ---------------------------------------------------------------------------
__global__ void build_m(const float* __restrict__ h, float* __restrict__ msc)
{
    int b = threadIdx.x;
    if (b < 16) {
        float m[9];
#pragma unroll
        for (int i = 0; i < 3; ++i)
#pragma unroll
            for (int j = 0; j < 3; ++j) m[i * 3 + j] = fabsf(h[b * 9 + j * 3 + i]);
        float n = 0.f;
#pragma unroll
        for (int i = 0; i < 3; ++i) {
            float r = m[i * 3] + m[i * 3 + 1] + m[i * 3 + 2];
            n = fmaxf(n, r);
        }
        n += 1e-4f;
        float inv = 1.f / n;
#pragma unroll
        for (int k = 0; k < 9; ++k) msc[b * 9 + k] = m[k] * inv;
    }
}

// ---------------------------------------------------------------------------
// est[b] = inv(msc[b]) @ |ill[b]|
// ---------------------------------------------------------------------------
__global__ void final_est(const float* __restrict__ msc, const float* __restrict__ ill,
                          float* __restrict__ out)
{
    int bidx = threadIdx.x;
    if (bidx < 16) {
        const float* m = msc + bidx * 9;
        float a = m[0], b = m[1], c = m[2];
        float d = m[3], e = m[4], f = m[5];
        float g = m[6], h = m[7], i = m[8];
        float A = e * i - f * h, B = f * g - d * i, C = d * h - e * g;
        float D = c * h - b * i, E = a * i - c * g, F = b * g - a * h;
        float G = b * f - c * e, H = c * d - a * f, I = a * e - b * d;
        float det = a * A + b * B + c * C;
        float inv_det = 1.f / det;
        float x0 = fabsf(ill[bidx * 3 + 0]);
        float x1 = fabsf(ill[bidx * 3 + 1]);
        float x2 = fabsf(ill[bidx * 3 + 2]);
        out[bidx * 3 + 0] = (A * x0 + D * x1 + G * x2) * inv_det;
        out[bidx * 3 + 1] = (B * x0 + E * x1 + H * x2) * inv_det;
        out[bidx * 3 + 2] = (C * x0 + F * x1 + I * x2) * inv_det;
    }
}

extern "C" void kernel_launch(void* const* d_in, const int* in_sizes, int n_in,
                              void* d_out, int out_size, void* d_ws, size_t ws_size,
                              hipStream_t stream)
{
    (void)in_sizes; (void)n_in; (void)out_size; (void)ws_size;
    const float* image = (const float*)d_in[0];
    const float* su_s  = (const float*)d_in[1];
    const float* sv_s  = (const float*)d_in[2];
    const float* c_s   = (const float*)d_in[3];
    const float* w1_s  = (const float*)d_in[4];
    const float* b1_s  = (const float*)d_in[5];
    const float* w2_s  = (const float*)d_in[6];
    const float* b2_s  = (const float*)d_in[7];
    const float* w3_s  = (const float*)d_in[8];
    const float* b3_s  = (const float*)d_in[9];
    const float* fc_s  = (const float*)d_in[10];
    const float* su_i  = (const float*)d_in[11];
    const float* sv_i  = (const float*)d_in[12];
    const float* c_i   = (const float*)d_in[13];
    const float* w1_i  = (const float*)d_in[14];
    const float* b1_i  = (const float*)d_in[15];
    const float* w2_i  = (const float*)d_in[16];
    const float* b2_i  = (const float*)d_in[17];
    const float* w3_i  = (const float*)d_in[18];
    const float* b3_i  = (const float*)d_in[19];
    const float* fc_i  = (const float*)d_in[20];

    float* W    = (float*)d_ws;
    float* hist = W;                              // 16*3*61*61   = 178608
    float* o1   = hist + 178608;                  // 16*128*29*29 = 1722368
    float* o2   = o1 + 1722368;                   // 16*256*14*14 = 802816
    float* o3   = o2 + 802816;                    // 16*512*13*13 = 1384448
    float* hd   = o3 + 1384448;                   // 16*9 head output
    float* msc  = hd + 144;                       // 16*9 scaled matrix

    const size_t HIST_BYTES = 178608u * sizeof(float);
    const int FCK = 512 * 13 * 13;
    const int O2_TOT = 16 * 256 * 196;
    const int O3_TOT = 16 * 512 * 169;

    // ================= sensor branch =================
    hipMemsetAsync(hist, 0, HIST_BYTES, stream);
    hipMemsetAsync(o2, 0, (size_t)O2_TOT * 4, stream);
    hipMemsetAsync(o3, 0, (size_t)O3_TOT * 4, stream);
    hipMemsetAsync(hd, 0, 144 * 4, stream);
    hist_mfma<<<dim3(48, HSP), 256, 0, stream>>>(image, su_s, sv_s, c_s, nullptr, hist);
    norm_hist<<<16, 256, 0, stream>>>(hist);
    conv_relu<3, 128, 5, 2, 61, 29, 16, 3, 4><<<dim3(16, 8), 256, 0, stream>>>(hist, w1_s, b1_s, o1);
    conv_split<128, 256, 3, 2, 29, 14, 64, 16, 4, 8, 4><<<dim3(16, 4, 4), 256, 0, stream>>>(o1, w2_s, o2);
    bias_relu<<<1024, 256, 0, stream>>>(o2, b2_s, 256, 196, O2_TOT);
    conv_split<256, 512, 2, 1, 14, 13, 64, 16, 3, 16, 4><<<dim3(16, 8, 4), 256, 0, stream>>>(o2, w3_s, o3);
    bias_relu<<<1024, 256, 0, stream>>>(o3, b3_s, 512, 169, O3_TOT);
    fc_atomic<<<dim3(16, 9, 8), 256, 0, stream>>>(o3, fc_s, hd, FCK, 9, 8);
    build_m<<<1, 64, 0, stream>>>(hd, msc);

    // ================= illuminant branch =================
    hipMemsetAsync(hist, 0, HIST_BYTES, stream);
    hipMemsetAsync(o2, 0, (size_t)O2_TOT * 4, stream);
    hipMemsetAsync(o3, 0, (size_t)O3_TOT * 4, stream);
    hipMemsetAsync(hd, 0, 144 * 4, stream);
    hist_mfma<<<dim3(48, HSP), 256, 0, stream>>>(image, su_i, sv_i, c_i, msc, hist);
    norm_hist<<<16, 256, 0, stream>>>(hist);
    conv_relu<3, 128, 5, 2, 61, 29, 16, 3, 4><<<dim3(16, 8), 256, 0, stream>>>(hist, w1_i, b1_i, o1);
    conv_split<128, 256, 3, 2, 29, 14, 64, 16, 4, 8, 4><<<dim3(16, 4, 4), 256, 0, stream>>>(o1, w2_i, o2);
    bias_relu<<<1024, 256, 0, stream>>>(o2, b2_i, 256, 196, O2_TOT);
    conv_split<256, 512, 2, 1, 14, 13, 64, 16, 3, 16, 4><<<dim3(16, 8, 4), 256, 0, stream>>>(o2, w3_i, o3);
    bias_relu<<<1024, 256, 0, stream>>>(o3, b3_i, 512, 169, O3_TOT);
    fc_atomic<<<dim3(16, 3, 8), 256, 0, stream>>>(o3, fc_i, hd, FCK, 3, 8);
    final_est<<<1, 64, 0, stream>>>(msc, hd, (float*)d_out);
}